// Round 10
// baseline (40.232 us; speedup 1.0000x reference)
//
#include <hip/hip_runtime.h>

#define D_MODEL   256
#define NUM_TYPES 7
#define BATCH     2
#define NLANES    512
#define LSTR      264   // f16 LDS row stride: 528B/row -> 2-way bank max (free, m136)

typedef _Float16  f16x8   __attribute__((ext_vector_type(8)));
typedef float     floatx4 __attribute__((ext_vector_type(4)));

// ws: Hi16 @ 0 (512 KB) = f16(x@W1a+b1); Hj16 @ 512 KB (512 KB) = f16(x@W1b);
//     w2f @ 1 MB (8 KB) = W2^T MFMA A-fragments (slot = kc*64+lane, f16x8 each).

// ---------------- Kernel 1: H16 = f16(x @ [W1a|W1b] (+b1)) via f16 MFMA ----------
// (r5-proven; one block additionally writes the w2 fragment table)
__global__ __launch_bounds__(256) void k1_mfma(
    const float* __restrict__ x, const float* __restrict__ W1,
    const float* __restrict__ b1, const float* __restrict__ W2,
    _Float16* __restrict__ Hi16, _Float16* __restrict__ Hj16,
    _Float16* __restrict__ w2f)
{
    const int tid  = threadIdx.x, lane = tid & 63, w = tid >> 6;
    const int nt   = blockIdx.x;                  // 0..31 ; half = nt>>4
    const int half = nt >> 4;
    const int nc   = (nt & 15) * 16;
    const int m0   = (blockIdx.y * 4 + w) * 16;
    const int jr   = lane & 15, g = lane >> 4, ks = g * 8;

    const float* xrow = x + (size_t)(m0 + jr) * D_MODEL + ks;
    const float* wb   = W1 + (size_t)(half * D_MODEL + ks) * D_MODEL + nc + jr;

    floatx4 acc = {0.f, 0.f, 0.f, 0.f};
    #pragma unroll
    for (int kc = 0; kc < 8; ++kc) {
        const float4 qa = *(const float4*)(xrow + kc * 32);
        const float4 qb = *(const float4*)(xrow + kc * 32 + 4);
        f16x8 a, bfr;
        a[0] = (_Float16)qa.x; a[1] = (_Float16)qa.y;
        a[2] = (_Float16)qa.z; a[3] = (_Float16)qa.w;
        a[4] = (_Float16)qb.x; a[5] = (_Float16)qb.y;
        a[6] = (_Float16)qb.z; a[7] = (_Float16)qb.w;
        const float* wp = wb + (size_t)(kc * 32) * D_MODEL;
        #pragma unroll
        for (int e = 0; e < 8; ++e)
            bfr[e] = (_Float16)wp[(size_t)e * D_MODEL];
        acc = __builtin_amdgcn_mfma_f32_16x16x32_f16(a, bfr, acc, 0, 0, 0);
    }

    _Float16* Hb = half ? Hj16 : Hi16;
    const float bias = half ? 0.f : b1[nc + jr];
    #pragma unroll
    for (int r = 0; r < 4; ++r)
        Hb[(size_t)(m0 + g * 4 + r) * D_MODEL + nc + jr] = (_Float16)(acc[r] + bias);

    // ---- one block builds the W2^T fragment table (8 KB) ----
    if (nt == 0 && blockIdx.y == 0) {
        #pragma unroll
        for (int s0 = 0; s0 < 2; ++s0) {
            const int s   = tid + s0 * 256;       // slot 0..511
            const int l2  = s & 63, kc2 = s >> 6;
            const int t2  = l2 & 15, ks2 = (l2 >> 4) * 8;
            f16x8 frag;
            #pragma unroll
            for (int e = 0; e < 8; ++e) {
                const int k = kc2 * 32 + ks2 + e;
                frag[e] = (t2 < NUM_TYPES)
                    ? (_Float16)W2[(size_t)k * NUM_TYPES + t2] : (_Float16)0.f;
            }
            *(f16x8*)(w2f + (size_t)s * 8) = frag;
        }
    }
}

// ---------------- Kernel 2: out[b,i,j,:] = relu(Hi[i]+Hj[j]) @ W2 + b2 ----------
// Tile 16i x 32j, 256 thr = 4 waves, grid (16,32,2) = 1024 blocks (~4/CU).
// Hj ONLY in LDS (17 KB); Hi read straight from global (L2-hot broadcast:
// 16-lane groups share the address -> 4x16B per wave-load, no LDS port use).
// All 8 w2 frags resident (loaded pre-barrier); hjrA/hjrB ping-pong across kch;
// hA/hB ping-pong across u. Every load window hides under 8 MFMA + 16 pk ops.
__global__ __launch_bounds__(256, 4) void k2_pair(
    const _Float16* __restrict__ Hi16, const _Float16* __restrict__ Hj16,
    const _Float16* __restrict__ w2f, const float* __restrict__ b2,
    float* __restrict__ out)
{
    __shared__ __align__(16) _Float16 hjs[32][LSTR];

    const int tid  = threadIdx.x;       // 0..255
    const int lane = tid & 63, w = tid >> 6;
    const int b    = blockIdx.z;
    const int j0   = blockIdx.x * 32;
    const int i0   = blockIdx.y * 16;
    const int jr   = lane & 15, g = lane >> 4, ks = g * 8;

    // ---- stage 32 Hj rows (16 KB), coalesced f16x8 ----
    #pragma unroll
    for (int q = 0; q < 4; ++q) {
        const int gg = tid + q * 256;   // granule 0..1023
        const int r  = gg >> 5;         // row 0..31
        const int c  = (gg & 31) * 8;   // f16 col
        *(f16x8*)&hjs[r][c] = *(const f16x8*)(
            Hj16 + (size_t)(b * NLANES + j0 + r) * D_MODEL + c);
    }

    // ---- all 8 W2^T A-frags resident (32 VGPR); loads hide under staging ----
    const f16x8* w2fp = (const f16x8*)w2f + lane;
    f16x8 w2r[8];
    #pragma unroll
    for (int kc = 0; kc < 8; ++kc)
        w2r[kc] = w2fp[kc * 64];

    const int tb = g * 4;
    float bias2[4];
    #pragma unroll
    for (int r = 0; r < 4; ++r)
        bias2[r] = (tb + r < NUM_TYPES) ? b2[tb + r] : 0.f;

    __syncthreads();

    const int ig = w;                   // wave's 4 i's: i0 + ig*4 + u
    const _Float16* hiBase = Hi16 + (size_t)(b * NLANES + i0 + ig * 4) * D_MODEL + ks;

#define LOAD_HI(DST, U, KB)                                                     \
    do { _Pragma("unroll") for (int kc = 0; kc < 4; ++kc)                       \
        DST[kc] = *(const f16x8*)(hiBase + (size_t)(U) * D_MODEL + (KB) + kc * 32); \
    } while (0)

#define LOAD_HJ(DST, JG, KB)                                                    \
    do { _Pragma("unroll") for (int kc = 0; kc < 4; ++kc)                       \
        DST[kc] = *(const f16x8*)&hjs[(JG) * 16 + jr][(KB) + kc * 32 + ks];     \
    } while (0)

#define COMPUTE_U(HI, HJ, ACC, KH)                                              \
    do { _Pragma("unroll") for (int kc = 0; kc < 4; ++kc) {                     \
        const f16x8 z = {};                                                     \
        f16x8 s = __builtin_elementwise_max(HI[kc] + HJ[kc], z);                \
        ACC = __builtin_amdgcn_mfma_f32_16x16x32_f16(                           \
            w2r[(KH) * 4 + kc], s, ACC, 0, 0, 0);                               \
    } } while (0)

    #pragma unroll
    for (int jg = 0; jg < 2; ++jg) {
        floatx4 acc0 = {0.f,0.f,0.f,0.f}, acc1 = {0.f,0.f,0.f,0.f};
        floatx4 acc2 = {0.f,0.f,0.f,0.f}, acc3 = {0.f,0.f,0.f,0.f};
        f16x8 hjrA[4], hjrB[4], hA[4], hB[4];

        LOAD_HJ(hjrA, jg, 0);                 // kch0 j-frags (4 ds_read_b128)
        LOAD_HI(hA, 0, 0);                    // u0 kch0 (global broadcast)
        LOAD_HI(hB, 1, 0);                    // u1 kch0

        COMPUTE_U(hA, hjrA, acc0, 0);  LOAD_HI(hA, 2, 0);
        COMPUTE_U(hB, hjrA, acc1, 0);  LOAD_HI(hB, 3, 0);
        LOAD_HJ(hjrB, jg, 128);               // kch1 j-frags, hides under u2/u3
        COMPUTE_U(hA, hjrA, acc2, 0);  LOAD_HI(hA, 0, 128);
        COMPUTE_U(hB, hjrA, acc3, 0);  LOAD_HI(hB, 1, 128);
        COMPUTE_U(hA, hjrB, acc0, 1);  LOAD_HI(hA, 2, 128);
        COMPUTE_U(hB, hjrB, acc1, 1);  LOAD_HI(hB, 3, 128);
        COMPUTE_U(hA, hjrB, acc2, 1);
        COMPUTE_U(hB, hjrB, acc3, 1);

        // ---- store this jg: lane<32 holds D[tb..tb+3][jr] (exact-WRITE) ----
        if (lane < 32) {
            const floatx4 av[4] = {acc0, acc1, acc2, acc3};
            #pragma unroll
            for (int u = 0; u < 4; ++u) {
                const int i = i0 + ig * 4 + u;
                const int j = j0 + jg * 16 + jr;
                float* op = out + ((size_t)(b * NLANES + i) * NLANES + j) * NUM_TYPES + tb;
                if (tb == 0) {
                    float v4[4] = { av[u][0] + bias2[0], av[u][1] + bias2[1],
                                    av[u][2] + bias2[2], av[u][3] + bias2[3] };
                    __builtin_memcpy(op, v4, 16);
                } else {
                    float v2[2] = { av[u][0] + bias2[0], av[u][1] + bias2[1] };
                    __builtin_memcpy(op, v2, 8);
                    op[2] = av[u][2] + bias2[2];
                }
            }
        }
    }
#undef LOAD_HI
#undef LOAD_HJ
#undef COMPUTE_U
}

extern "C" void kernel_launch(void* const* d_in, const int* in_sizes, int n_in,
                              void* d_out, int out_size, void* d_ws, size_t ws_size,
                              hipStream_t stream) {
    const float* x  = (const float*)d_in[0];   // (2,512,256)
    const float* W1 = (const float*)d_in[1];   // (512,256)
    const float* b1 = (const float*)d_in[2];   // (256)
    const float* W2 = (const float*)d_in[3];   // (256,7)
    const float* b2 = (const float*)d_in[4];   // (7)
    float* out = (float*)d_out;                // (2,512,512,7) fp32

    char* ws = (char*)d_ws;
    _Float16* Hi16 = (_Float16*)ws;
    _Float16* Hj16 = (_Float16*)(ws + 512u * 1024u);
    _Float16* w2f  = (_Float16*)(ws + 1024u * 1024u);

    k1_mfma<<<dim3(32, 16), 256, 0, stream>>>(x, W1, b1, W2, Hi16, Hj16, w2f);
    k2_pair<<<dim3(NLANES / 32, NLANES / 16, BATCH), 256, 0, stream>>>(
        Hi16, Hj16, w2f, b2, out);
}

// Round 11
// 19.955 us; speedup vs baseline: 2.0162x; 2.0162x over previous
//
#include <hip/hip_runtime.h>

#define D_MODEL   256
#define NUM_TYPES 7
#define BATCH     2
#define NLANES    512
#define LSTR      264   // f16 LDS row stride: 528B/row -> 2-way bank max (free, m136)

typedef _Float16  f16x8   __attribute__((ext_vector_type(8)));
typedef float     floatx4 __attribute__((ext_vector_type(4)));

// ws: Hi16 @ 0 (512 KB) = f16(x@W1a+b1); Hj16 @ 512 KB (512 KB) = f16(x@W1b);
//     w2f @ 1 MB (8 KB) = W2^T MFMA A-fragments (slot = kc*64+lane, f16x8 each).

// ---------------- Kernel 1: H16 = f16(x @ [W1a|W1b] (+b1)) via f16 MFMA ----------
// NEW: x-tile staged COALESCED into LDS as f16 (was: per-lane scattered global).
// Block = 64 rows x 16 cols of one half. A-frags via ds_read_b128.
__global__ __launch_bounds__(256) void k1_mfma(
    const float* __restrict__ x, const float* __restrict__ W1,
    const float* __restrict__ b1, const float* __restrict__ W2,
    _Float16* __restrict__ Hi16, _Float16* __restrict__ Hj16,
    _Float16* __restrict__ w2f)
{
    __shared__ __align__(16) _Float16 xs[64][LSTR];   // 33 KB

    const int tid  = threadIdx.x, lane = tid & 63, w = tid >> 6;
    const int nt   = blockIdx.x;                  // 0..31 ; half = nt>>4
    const int half = nt >> 4;
    const int nc   = (nt & 15) * 16;
    const int r0   = blockIdx.y * 64;             // row-tile base
    const int jr   = lane & 15, g = lane >> 4, ks = g * 8;

    // ---- stage 64 x-rows (64 KB f32 -> 32 KB f16), fully coalesced ----
    {
        const float4* xsrc = (const float4*)(x + (size_t)r0 * D_MODEL);
        #pragma unroll
        for (int q = 0; q < 8; ++q) {
            const int gg = q * 512 + tid * 2;     // float4 granule (pair start)
            const int r  = gg >> 6;               // row 0..63
            const int c4 = gg & 63;               // even
            const float4 v0 = xsrc[gg];
            const float4 v1 = xsrc[gg + 1];
            f16x8 o;
            o[0] = (_Float16)v0.x; o[1] = (_Float16)v0.y;
            o[2] = (_Float16)v0.z; o[3] = (_Float16)v0.w;
            o[4] = (_Float16)v1.x; o[5] = (_Float16)v1.y;
            o[6] = (_Float16)v1.z; o[7] = (_Float16)v1.w;
            *(f16x8*)&xs[r][c4 * 4] = o;
        }
    }

    // ---- B-frags: W1 cols nc..nc+15, strided (L2-hot); hides under staging ----
    f16x8 w1f[8];
    {
        const float* wb = W1 + (size_t)(half * D_MODEL + ks) * D_MODEL + nc + jr;
        #pragma unroll
        for (int kc = 0; kc < 8; ++kc)
            #pragma unroll
            for (int e = 0; e < 8; ++e)
                w1f[kc][e] = (_Float16)wb[(size_t)(kc * 32 + e) * D_MODEL];
    }

    __syncthreads();

    // ---- wave w: rows r0 + w*16 .. +15 ----
    floatx4 acc = {0.f, 0.f, 0.f, 0.f};
    #pragma unroll
    for (int kc = 0; kc < 8; ++kc) {
        const f16x8 a = *(const f16x8*)&xs[w * 16 + jr][kc * 32 + ks];
        acc = __builtin_amdgcn_mfma_f32_16x16x32_f16(a, w1f[kc], acc, 0, 0, 0);
    }

    _Float16* Hb = half ? Hj16 : Hi16;
    const float bias = half ? 0.f : b1[nc + jr];
    const int m0 = r0 + w * 16;
    #pragma unroll
    for (int r = 0; r < 4; ++r)
        Hb[(size_t)(m0 + g * 4 + r) * D_MODEL + nc + jr] = (_Float16)(acc[r] + bias);

    // ---- one block builds the W2^T fragment table (8 KB) ----
    if (nt == 0 && blockIdx.y == 0) {
        #pragma unroll
        for (int s0 = 0; s0 < 2; ++s0) {
            const int s   = tid + s0 * 256;       // slot 0..511
            const int l2  = s & 63, kc2 = s >> 6;
            const int t2  = l2 & 15, ks2 = (l2 >> 4) * 8;
            f16x8 frag;
            #pragma unroll
            for (int e = 0; e < 8; ++e) {
                const int k = kc2 * 32 + ks2 + e;
                frag[e] = (t2 < NUM_TYPES)
                    ? (_Float16)W2[(size_t)k * NUM_TYPES + t2] : (_Float16)0.f;
            }
            *(f16x8*)(w2f + (size_t)s * 8) = frag;
        }
    }
}

// ---------------- Kernel 2: out[b,i,j,:] = relu(Hi[i]+Hj[j]) @ W2 + b2 ----------
// BYTE-IDENTICAL to round 8's 22.6-us version (proven best).
// Tile 16i x 32j, 256 thr = 4 waves, grid (16,32,2) = 1024 blocks (~4/CU).
// Wave = 4 i's x BOTH j-groups. hA/hB ping-pong hides ds latency under MFMAs.
#define COMPUTE_U(H, U)                                                          \
    do {                                                                         \
        _Pragma("unroll")                                                        \
        for (int kc = 0; kc < 4; ++kc) {                                         \
            const f16x8 z = {};                                                  \
            f16x8 s0 = __builtin_elementwise_max(H[kc] + hjr0[kc], z);           \
            acc##U[0] = __builtin_amdgcn_mfma_f32_16x16x32_f16(                  \
                w2h[kc], s0, acc##U[0], 0, 0, 0);                                \
            f16x8 s1 = __builtin_elementwise_max(H[kc] + hjr1[kc], z);           \
            acc##U[1] = __builtin_amdgcn_mfma_f32_16x16x32_f16(                  \
                w2h[kc], s1, acc##U[1], 0, 0, 0);                                \
        }                                                                        \
    } while (0)

__global__ __launch_bounds__(256, 4) void k2_pair(
    const _Float16* __restrict__ Hi16, const _Float16* __restrict__ Hj16,
    const _Float16* __restrict__ w2f, const float* __restrict__ b2,
    float* __restrict__ out)
{
    __shared__ _Float16 hs[48][LSTR];   // rows 0..15: Hi(i0+r); 16..47: Hj(j0+r-16)

    const int tid  = threadIdx.x;       // 0..255
    const int lane = tid & 63, w = tid >> 6;
    const int b    = blockIdx.z;
    const int j0   = blockIdx.x * 32;
    const int i0   = blockIdx.y * 16;
    const int jr   = lane & 15, g = lane >> 4, ks = g * 8;

    // ---- stage 48 rows (24 KB of H), uniform Hi / Hj halves, coalesced ----
    #pragma unroll
    for (int q = 0; q < 2; ++q) {       // granules 0..511 -> Hi rows 0..15
        const int gg = tid + q * 256;
        const int r  = gg >> 5;
        const int c  = (gg & 31) * 8;
        *(f16x8*)&hs[r][c] = *(const f16x8*)(
            Hi16 + (size_t)(b * NLANES + i0 + r) * D_MODEL + c);
    }
    #pragma unroll
    for (int q = 0; q < 4; ++q) {       // granules 0..1023 -> Hj rows 16..47
        const int gg = tid + q * 256;
        const int r  = gg >> 5;
        const int c  = (gg & 31) * 8;
        *(f16x8*)&hs[16 + r][c] = *(const f16x8*)(
            Hj16 + (size_t)(b * NLANES + j0 + r) * D_MODEL + c);
    }

    const int tb = g * 4;
    float bias2[4];
    #pragma unroll
    for (int r = 0; r < 4; ++r)
        bias2[r] = (tb + r < NUM_TYPES) ? b2[tb + r] : 0.f;

    __syncthreads();

    const int ig = w;                   // wave's 4 i's: i0 + ig*4 + u
    const f16x8* w2fp = (const f16x8*)w2f + lane;   // + (kch*4+kc)*64

    floatx4 acc0[2], acc1[2], acc2[2], acc3[2];
    #pragma unroll
    for (int jg = 0; jg < 2; ++jg) {
        acc0[jg] = (floatx4){0.f, 0.f, 0.f, 0.f};
        acc1[jg] = (floatx4){0.f, 0.f, 0.f, 0.f};
        acc2[jg] = (floatx4){0.f, 0.f, 0.f, 0.f};
        acc3[jg] = (floatx4){0.f, 0.f, 0.f, 0.f};
    }

    #pragma unroll
    for (int kch = 0; kch < 2; ++kch) {
        const int kb = kch * 128;       // f16 col base of this k-half

        f16x8 w2h[4];                   // this half's A-frags: coalesced b128
        #pragma unroll
        for (int kc = 0; kc < 4; ++kc)
            w2h[kc] = w2fp[(kch * 4 + kc) * 64];

        f16x8 hjr0[4], hjr1[4];         // both j-groups, resident
        #pragma unroll
        for (int kc = 0; kc < 4; ++kc) {
            hjr0[kc] = *(const f16x8*)&hs[16 + jr][kb + kc * 32 + ks];
            hjr1[kc] = *(const f16x8*)&hs[32 + jr][kb + kc * 32 + ks];
        }

        f16x8 hA[4], hB[4];             // ping-pong i-fragments
        #pragma unroll
        for (int kc = 0; kc < 4; ++kc)
            hA[kc] = *(const f16x8*)&hs[ig * 4 + 0][kb + kc * 32 + ks];
        #pragma unroll
        for (int kc = 0; kc < 4; ++kc)
            hB[kc] = *(const f16x8*)&hs[ig * 4 + 1][kb + kc * 32 + ks];

        COMPUTE_U(hA, 0);               // u=0
        #pragma unroll
        for (int kc = 0; kc < 4; ++kc)  // refill hA for u=2 (hides under u=1)
            hA[kc] = *(const f16x8*)&hs[ig * 4 + 2][kb + kc * 32 + ks];
        COMPUTE_U(hB, 1);               // u=1
        #pragma unroll
        for (int kc = 0; kc < 4; ++kc)  // refill hB for u=3 (hides under u=2)
            hB[kc] = *(const f16x8*)&hs[ig * 4 + 3][kb + kc * 32 + ks];
        COMPUTE_U(hA, 2);               // u=2
        COMPUTE_U(hB, 3);               // u=3
    }

    // ---- store: lane<32 holds D[tb..tb+3][jr] (proven exact-WRITE pattern) ----
    if (lane < 32) {
        floatx4* accs[4] = {acc0, acc1, acc2, acc3};
        #pragma unroll
        for (int u = 0; u < 4; ++u) {
            const int i = i0 + ig * 4 + u;
            #pragma unroll
            for (int jg = 0; jg < 2; ++jg) {
                const floatx4 a = accs[u][jg];
                const int j = j0 + jg * 16 + jr;
                float* op = out + ((size_t)(b * NLANES + i) * NLANES + j) * NUM_TYPES + tb;
                if (tb == 0) {
                    float v4[4] = { a[0] + bias2[0], a[1] + bias2[1],
                                    a[2] + bias2[2], a[3] + bias2[3] };
                    __builtin_memcpy(op, v4, 16);
                } else {
                    float v2[2] = { a[0] + bias2[0], a[1] + bias2[1] };
                    __builtin_memcpy(op, v2, 8);
                    op[2] = a[2] + bias2[2];
                }
            }
        }
    }
}

extern "C" void kernel_launch(void* const* d_in, const int* in_sizes, int n_in,
                              void* d_out, int out_size, void* d_ws, size_t ws_size,
                              hipStream_t stream) {
    const float* x  = (const float*)d_in[0];   // (2,512,256)
    const float* W1 = (const float*)d_in[1];   // (512,256)
    const float* b1 = (const float*)d_in[2];   // (256)
    const float* W2 = (const float*)d_in[3];   // (256,7)
    const float* b2 = (const float*)d_in[4];   // (7)
    float* out = (float*)d_out;                // (2,512,512,7) fp32

    char* ws = (char*)d_ws;
    _Float16* Hi16 = (_Float16*)ws;
    _Float16* Hj16 = (_Float16*)(ws + 512u * 1024u);
    _Float16* w2f  = (_Float16*)(ws + 1024u * 1024u);

    k1_mfma<<<dim3(32, 16), 256, 0, stream>>>(x, W1, b1, W2, Hi16, Hj16, w2f);
    k2_pair<<<dim3(NLANES / 32, NLANES / 16, BATCH), 256, 0, stream>>>(
        Hi16, Hj16, w2f, b2, out);
}